// Round 14
// baseline (158.055 us; speedup 1.0000x reference)
//
#include <hip/hip_runtime.h>

#define NMS_NUM_CLASSES 16
#define NMS_N 2048
#define NMS_IOU_TH 0.5f
#define NMS_SCORE_TH 0.05f
#define NMS_MAX_DET 100
#define NMS_MAX_PER_CLASS 100
#define NMS_NS (NMS_NUM_CLASSES * NMS_MAX_PER_CLASS)   // 1600
#define NMS_TILE 128
#define NMS_TW 4                     // u32 words per sup row (128 bits)

// SESSION PITFALLS (r1-r13):
//  * float4 casts on __shared__ float -> ds_read_b128 misalignment fault.
//  * All kernels with u64 LDS arrays or LDS pointer casts died; all kernels
//    using only declared-type b32/u8 LDS arrays passed. This file uses ONLY
//    declared __shared__ float/uint/uchar arrays, scalar b32/u8 access.

// ---------------------------------------------------------------------------
// Kernel 1: one block per (image, class). Compact -> rank sort (r12-proven)
// -> tiled bitmask greedy NMS with u32 sup-matrix (parallel IoU phase +
// thread-0 register mask reduction) -> wave-scan emit (r12-proven).
// ---------------------------------------------------------------------------
__global__ __launch_bounds__(256) void nms_per_class_kernel(
    const float* __restrict__ pred,   // [B, N, 6] x1,y1,x2,y2,cls,score
    float* __restrict__ ws_scores,    // [B, 1600]
    float* __restrict__ ws_boxes,     // [B, 1600, 4]
    float* __restrict__ out,          // [B*600] rows + [B] nvalid
    int B)
{
    const int b = blockIdx.x / NMS_NUM_CLASSES;
    const int c = blockIdx.x % NMS_NUM_CLASSES;
    const float* p = pred + (size_t)b * NMS_N * 6;

    // zero-init output for this image (k2 is a later dispatch on the stream)
    if (c == 0) {
        float* ob = out + (size_t)b * NMS_MAX_DET * 6;
        for (int t = threadIdx.x; t < NMS_MAX_DET * 6; t += blockDim.x) ob[t] = 0.0f;
        if (threadIdx.x == 0) out[(size_t)B * NMS_MAX_DET * 6 + b] = 0.0f;
    }

    // unsorted candidate arrays
    __shared__ float s_scu[NMS_N];
    __shared__ int   s_ixu[NMS_N];
    __shared__ float s_bxu[NMS_N * 4];
    // sorted candidate arrays
    __shared__ float s_sc[NMS_N];
    __shared__ float s_bx[NMS_N * 4];
    __shared__ unsigned char s_keep[NMS_N];
    __shared__ unsigned int s_sup[NMS_TILE * NMS_TW];   // 2 KB, u32 only
    __shared__ int s_m;
    __shared__ int s_part[256];
    __shared__ int s_total;

    if (threadIdx.x == 0) s_m = 0;
    __syncthreads();

    // --- compact candidates of class c with score > TH (r12-proven) ---
    const float2* p2 = (const float2*)p;   // row i = p2[3i], p2[3i+1], p2[3i+2]
    for (int i = threadIdx.x; i < NMS_N; i += blockDim.x) {
        float2 v0 = p2[i * 3 + 0];   // x1, y1
        float2 v1 = p2[i * 3 + 1];   // x2, y2
        float2 v2 = p2[i * 3 + 2];   // cls, score
        if ((int)v2.x == c && v2.y > NMS_SCORE_TH) {
            int pos = atomicAdd(&s_m, 1);
            s_scu[pos] = v2.y;
            s_ixu[pos] = i;
            s_bxu[pos * 4 + 0] = v0.x;
            s_bxu[pos * 4 + 1] = v0.y;
            s_bxu[pos * 4 + 2] = v1.x;
            s_bxu[pos * 4 + 3] = v1.y;
        }
    }
    __syncthreads();
    const int M = s_m;

    // --- rank sort: desc score, ties -> lower original index (r12-proven) ---
    for (int q = threadIdx.x; q < M; q += blockDim.x) {
        float sq = s_scu[q];
        int   iq = s_ixu[q];
        int rk = 0;
        for (int j = 0; j < M; ++j) {
            float sj = s_scu[j];
            rk += (sj > sq) || (sj == sq && s_ixu[j] < iq);
        }
        s_sc[rk] = sq;
        s_bx[rk * 4 + 0] = s_bxu[q * 4 + 0];
        s_bx[rk * 4 + 1] = s_bxu[q * 4 + 1];
        s_bx[rk * 4 + 2] = s_bxu[q * 4 + 2];
        s_bx[rk * 4 + 3] = s_bxu[q * 4 + 3];
        s_keep[rk] = 1;
    }
    __syncthreads();

    // --- tiled bitmask greedy NMS (u32 words, 128-candidate tiles) ---
    for (int t0 = 0; t0 < M; t0 += NMS_TILE) {
        const int tm = (M - t0 < NMS_TILE) ? (M - t0) : NMS_TILE;

        // A0: suppression of this tile by kept candidates of earlier tiles.
        // Writes only s_keep[t0..t0+tm), reads s_keep[0..t0) -> no race.
        if (t0 > 0) {
            for (int j = threadIdx.x; j < tm; j += blockDim.x) {
                const int gj = t0 + j;
                float jx1 = s_bx[gj * 4 + 0], jy1 = s_bx[gj * 4 + 1];
                float jx2 = s_bx[gj * 4 + 2], jy2 = s_bx[gj * 4 + 3];
                float aj = (jy2 - jy1) * (jx2 - jx1);
                int dead = 0;
                for (int i = 0; i < t0 && !dead; ++i) {
                    if (!s_keep[i]) continue;
                    float ix1 = s_bx[i * 4 + 0], iy1 = s_bx[i * 4 + 1];
                    float ix2 = s_bx[i * 4 + 2], iy2 = s_bx[i * 4 + 3];
                    float ai = (iy2 - iy1) * (ix2 - ix1);
                    float ih = fminf(iy2, jy2) - fmaxf(iy1, jy1);
                    ih = fmaxf(ih, 0.0f);
                    float iw = fminf(ix2, jx2) - fmaxf(ix1, jx1);
                    iw = fmaxf(iw, 0.0f);
                    float inter = ih * iw;
                    float uni = ai + aj - inter;
                    float iou = (inter > 0.0f) ? inter / fmaxf(uni, 1e-08f) : 0.0f;
                    dead = iou > NMS_IOU_TH;
                }
                if (dead) s_keep[gj] = 0;
            }
            __syncthreads();
        }

        // A: intra-tile suppression matrix, one task per (row, u32-word)
        for (int idx = threadIdx.x; idx < tm * NMS_TW; idx += blockDim.x) {
            const int r = idx >> 2;          // row within tile
            const int w = idx & 3;           // word within row
            const int gi = t0 + r;
            const int jbase = t0 + (w << 5);
            int jcnt = (t0 + tm) - jbase;    // <=0 when word beyond tile
            if (jcnt > 32) jcnt = 32;
            unsigned int msk = 0;
            int start = gi + 1 - jbase;
            if (start < 0) start = 0;
            if (start < jcnt) {
                float ix1 = s_bx[gi * 4 + 0], iy1 = s_bx[gi * 4 + 1];
                float ix2 = s_bx[gi * 4 + 2], iy2 = s_bx[gi * 4 + 3];
                float ai = (iy2 - iy1) * (ix2 - ix1);
                for (int bb = start; bb < jcnt; ++bb) {
                    const int gj = jbase + bb;
                    float jx1 = s_bx[gj * 4 + 0], jy1 = s_bx[gj * 4 + 1];
                    float jx2 = s_bx[gj * 4 + 2], jy2 = s_bx[gj * 4 + 3];
                    float aj = (jy2 - jy1) * (jx2 - jx1);
                    float ih = fminf(iy2, jy2) - fmaxf(iy1, jy1);
                    ih = fmaxf(ih, 0.0f);
                    float iw = fminf(ix2, jx2) - fmaxf(ix1, jx1);
                    iw = fmaxf(iw, 0.0f);
                    float inter = ih * iw;
                    float uni = ai + aj - inter;
                    float iou = (inter > 0.0f) ? inter / fmaxf(uni, 1e-08f) : 0.0f;
                    if (iou > NMS_IOU_TH) msk |= (1u << bb);
                }
            }
            s_sup[r * NMS_TW + w] = msk;
        }
        __syncthreads();

        // B: thread-0 serial greedy over the tile; keep state in u32 regs.
        // Sup-row loads are statically addressed (r sweeps 0..tm-1), only the
        // AND-apply is predicated -> pipelines without a shfl/barrier chain.
        if (threadIdx.x == 0) {
            unsigned int kw0 = 0, kw1 = 0, kw2 = 0, kw3 = 0;
            for (int r = 0; r < tm; ++r)
                if (s_keep[t0 + r]) {
                    if (r < 32)       kw0 |= (1u << r);
                    else if (r < 64)  kw1 |= (1u << (r - 32));
                    else if (r < 96)  kw2 |= (1u << (r - 64));
                    else              kw3 |= (1u << (r - 96));
                }
            for (int r = 0; r < tm; ++r) {
                unsigned int bit;
                if (r < 32)       bit = (kw0 >> r) & 1u;
                else if (r < 64)  bit = (kw1 >> (r - 32)) & 1u;
                else if (r < 96)  bit = (kw2 >> (r - 64)) & 1u;
                else              bit = (kw3 >> (r - 96)) & 1u;
                if (bit) {
                    kw0 &= ~s_sup[r * NMS_TW + 0];
                    kw1 &= ~s_sup[r * NMS_TW + 1];
                    kw2 &= ~s_sup[r * NMS_TW + 2];
                    kw3 &= ~s_sup[r * NMS_TW + 3];
                }
            }
            for (int r = 0; r < tm; ++r) {
                unsigned int bit;
                if (r < 32)       bit = (kw0 >> r) & 1u;
                else if (r < 64)  bit = (kw1 >> (r - 32)) & 1u;
                else if (r < 96)  bit = (kw2 >> (r - 64)) & 1u;
                else              bit = (kw3 >> (r - 96)) & 1u;
                s_keep[t0 + r] = (unsigned char)bit;
            }
        }
        __syncthreads();
    }

    // --- emit top-100 kept in sorted order via wave-scan (r12-proven) ---
    const int chunk = (M + 255) / 256;           // contiguous slots per thread
    const int lo = threadIdx.x * chunk;
    const int hi = (lo + chunk < M) ? (lo + chunk) : M;
    int cnt = 0;
    for (int j = lo; j < hi; ++j) cnt += s_keep[j];
    s_part[threadIdx.x] = cnt;
    __syncthreads();
    if (threadIdx.x < 64) {
        const int base = threadIdx.x * 4;
        int v0 = s_part[base + 0], v1 = s_part[base + 1];
        int v2 = s_part[base + 2], v3 = s_part[base + 3];
        int sum = v0 + v1 + v2 + v3;
        int inc = sum;
        for (int off = 1; off < 64; off <<= 1) {
            int n = __shfl_up(inc, off, 64);
            if ((int)threadIdx.x >= off) inc += n;
        }
        int exc = inc - sum;
        s_part[base + 0] = exc;
        s_part[base + 1] = exc + v0;
        s_part[base + 2] = exc + v0 + v1;
        s_part[base + 3] = exc + v0 + v1 + v2;
        if (threadIdx.x == 63) s_total = inc;
    }
    __syncthreads();

    float* osc = ws_scores + ((size_t)b * NMS_NUM_CLASSES + c) * NMS_MAX_PER_CLASS;
    float* obx = ws_boxes + (((size_t)b * NMS_NUM_CLASSES + c) * NMS_MAX_PER_CLASS) * 4;
    int pos = s_part[threadIdx.x];
    for (int j = lo; j < hi; ++j) {
        if (s_keep[j]) {
            if (pos < NMS_MAX_PER_CLASS) {
                osc[pos] = s_sc[j];
                obx[pos * 4 + 0] = s_bx[j * 4 + 0];
                obx[pos * 4 + 1] = s_bx[j * 4 + 1];
                obx[pos * 4 + 2] = s_bx[j * 4 + 2];
                obx[pos * 4 + 3] = s_bx[j * 4 + 3];
            }
            pos++;
        }
    }
    // pad positions [total, 100) with -1
    if (threadIdx.x < NMS_MAX_PER_CLASS && threadIdx.x >= s_total)
        osc[threadIdx.x] = -1.0f;
}

// ---------------------------------------------------------------------------
// Kernel 2: one block per (image, class), 256 threads. Task-parallel partial
// ranks. BYTE-IDENTICAL to round-12 (passed, absmax 0).
// ---------------------------------------------------------------------------
__global__ __launch_bounds__(256) void nms_topk_kernel(
    const float* __restrict__ ws_scores,   // [B, 1600]
    const float* __restrict__ ws_boxes,    // [B, 1600, 4]
    float* __restrict__ out,               // [B*600] rows + [B] nvalid
    int B)
{
    const int b = blockIdx.x / NMS_NUM_CLASSES;
    const int c = blockIdx.x % NMS_NUM_CLASSES;
    const int cbase = c * NMS_MAX_PER_CLASS;
    __shared__ float s_sc[NMS_NS];
    __shared__ int s_rank[NMS_MAX_PER_CLASS];

    const float* isc = ws_scores + (size_t)b * NMS_NS;
    for (int t = threadIdx.x; t < NMS_NS; t += blockDim.x) s_sc[t] = isc[t];
    if (threadIdx.x < NMS_MAX_PER_CLASS) s_rank[threadIdx.x] = 0;
    __syncthreads();

    for (int task = threadIdx.x; task < NMS_MAX_PER_CLASS * 16; task += blockDim.x) {
        const int slot = task % NMS_MAX_PER_CLASS;
        const int chunk = task / NMS_MAX_PER_CLASS;
        const int flat = cbase + slot;
        const float s = s_sc[flat];
        const int j0 = chunk * 100;
        int rk = 0;
        for (int j = j0; j < j0 + 100; ++j) {
            float sj = s_sc[j];
            rk += (sj > s) || (sj == s && j < flat);
        }
        if (rk) atomicAdd(&s_rank[slot], rk);
    }
    __syncthreads();

    int is_top = 0;
    const int t = threadIdx.x;
    if (t < NMS_MAX_PER_CLASS) {
        const int slot = cbase + t;
        float s = s_sc[slot];
        if (s > NMS_SCORE_TH) {
            int rk = s_rank[t];
            if (rk < NMS_MAX_DET) {
                const float* bx = ws_boxes + ((size_t)b * NMS_NS + slot) * 4;
                float* row = out + (size_t)b * NMS_MAX_DET * 6 + rk * 6;
                row[0] = bx[0];
                row[1] = bx[1];
                row[2] = bx[2];
                row[3] = bx[3];
                row[4] = (float)c;
                row[5] = s;
                is_top = 1;
            }
        }
    }
    unsigned long long m = __ballot(is_top);
    if ((threadIdx.x & 63) == 0) {
        float cnt = (float)__popcll(m);
        if (cnt > 0.0f)
            atomicAdd(&out[(size_t)B * NMS_MAX_DET * 6 + b], cnt);
    }
}

extern "C" void kernel_launch(void* const* d_in, const int* in_sizes, int n_in,
                              void* d_out, int out_size, void* d_ws, size_t ws_size,
                              hipStream_t stream) {
    const float* pred = (const float*)d_in[0];
    const int B = in_sizes[0] / (NMS_N * 6);
    if (B <= 0) return;
    float* out = (float*)d_out;

    float* ws_scores = (float*)d_ws;
    float* ws_boxes = ws_scores + (size_t)B * NMS_NS;

    nms_per_class_kernel<<<dim3(B * NMS_NUM_CLASSES), dim3(256), 0, stream>>>(
        pred, ws_scores, ws_boxes, out, B);
    nms_topk_kernel<<<dim3(B * NMS_NUM_CLASSES), dim3(256), 0, stream>>>(
        ws_scores, ws_boxes, out, B);
}

// Round 15
// 130.706 us; speedup vs baseline: 1.2092x; 1.2092x over previous
//
#include <hip/hip_runtime.h>

#define NMS_NUM_CLASSES 16
#define NMS_N 2048
#define NMS_IOU_TH 0.5f
#define NMS_SCORE_TH 0.05f
#define NMS_MAX_DET 100
#define NMS_MAX_PER_CLASS 100
#define NMS_NS (NMS_NUM_CLASSES * NMS_MAX_PER_CLASS)   // 1600
#define NMS_TILE 128
#define NMS_TW 4                     // u32 words per column mask (128 bits)

// SESSION PITFALLS (r1-r14):
//  * float4 casts on __shared__ float -> ds_read_b128 misalignment fault.
//  * u64 LDS arrays / LDS pointer casts correlated with container deaths.
//    This file uses ONLY declared __shared__ float/uint/uchar arrays with
//    scalar b32/u8 access (r14-proven vocabulary).
//  * Serial NMS chains (barrier-per-i, shfl-chain, thread-0 mask walk) all
//    cost 45-65 us at M~122 — per-step LDS/barrier latency dominates. This
//    round replaces the serial phase with parallel Jacobi fixpoint.

// ---------------------------------------------------------------------------
// Kernel 1: one block per (image, class). Compact -> rank sort (r12-proven)
// -> per-tile: column suppressor masks (broadcast-friendly) + Jacobi
// fixpoint (== greedy; converges in ~depth rounds) -> wave-scan emit.
// ---------------------------------------------------------------------------
__global__ __launch_bounds__(256) void nms_per_class_kernel(
    const float* __restrict__ pred,   // [B, N, 6] x1,y1,x2,y2,cls,score
    float* __restrict__ ws_scores,    // [B, 1600]
    float* __restrict__ ws_boxes,     // [B, 1600, 4]
    float* __restrict__ out,          // [B*600] rows + [B] nvalid
    int B)
{
    const int b = blockIdx.x / NMS_NUM_CLASSES;
    const int c = blockIdx.x % NMS_NUM_CLASSES;
    const float* p = pred + (size_t)b * NMS_N * 6;

    // zero-init output for this image (k2 is a later dispatch on the stream)
    if (c == 0) {
        float* ob = out + (size_t)b * NMS_MAX_DET * 6;
        for (int t = threadIdx.x; t < NMS_MAX_DET * 6; t += blockDim.x) ob[t] = 0.0f;
        if (threadIdx.x == 0) out[(size_t)B * NMS_MAX_DET * 6 + b] = 0.0f;
    }

    // unsorted candidate arrays
    __shared__ float s_scu[NMS_N];
    __shared__ int   s_ixu[NMS_N];
    __shared__ float s_bxu[NMS_N * 4];
    // sorted candidate arrays
    __shared__ float s_sc[NMS_N];
    __shared__ float s_bx[NMS_N * 4];
    __shared__ unsigned char s_keep[NMS_N];
    __shared__ unsigned int s_supc[NMS_TILE * NMS_TW];  // column masks, 2 KB
    __shared__ unsigned int s_kwds[NMS_TW];             // published keep bits
    __shared__ int s_m;
    __shared__ int s_part[256];
    __shared__ int s_total;
    __shared__ int s_changed;

    if (threadIdx.x == 0) s_m = 0;
    __syncthreads();

    // --- compact candidates of class c with score > TH (r12-proven) ---
    const float2* p2 = (const float2*)p;   // row i = p2[3i], p2[3i+1], p2[3i+2]
    for (int i = threadIdx.x; i < NMS_N; i += blockDim.x) {
        float2 v0 = p2[i * 3 + 0];   // x1, y1
        float2 v1 = p2[i * 3 + 1];   // x2, y2
        float2 v2 = p2[i * 3 + 2];   // cls, score
        if ((int)v2.x == c && v2.y > NMS_SCORE_TH) {
            int pos = atomicAdd(&s_m, 1);
            s_scu[pos] = v2.y;
            s_ixu[pos] = i;
            s_bxu[pos * 4 + 0] = v0.x;
            s_bxu[pos * 4 + 1] = v0.y;
            s_bxu[pos * 4 + 2] = v1.x;
            s_bxu[pos * 4 + 3] = v1.y;
        }
    }
    __syncthreads();
    const int M = s_m;

    // --- rank sort: desc score, ties -> lower original index (r12-proven) ---
    for (int q = threadIdx.x; q < M; q += blockDim.x) {
        float sq = s_scu[q];
        int   iq = s_ixu[q];
        int rk = 0;
        for (int j = 0; j < M; ++j) {
            float sj = s_scu[j];
            rk += (sj > sq) || (sj == sq && s_ixu[j] < iq);
        }
        s_sc[rk] = sq;
        s_bx[rk * 4 + 0] = s_bxu[q * 4 + 0];
        s_bx[rk * 4 + 1] = s_bxu[q * 4 + 1];
        s_bx[rk * 4 + 2] = s_bxu[q * 4 + 2];
        s_bx[rk * 4 + 3] = s_bxu[q * 4 + 3];
        s_keep[rk] = 1;
    }
    __syncthreads();

    // --- tiled NMS: column masks + Jacobi fixpoint per tile ---
    for (int t0 = 0; t0 < M; t0 += NMS_TILE) {
        const int tm = (M - t0 < NMS_TILE) ? (M - t0) : NMS_TILE;

        // A0: suppression of this tile by kept candidates of earlier tiles
        // (final state). Writes s_keep[t0..), reads s_keep[0..t0) -> no race.
        if (t0 > 0) {
            for (int j = threadIdx.x; j < tm; j += blockDim.x) {
                const int gj = t0 + j;
                float jx1 = s_bx[gj * 4 + 0], jy1 = s_bx[gj * 4 + 1];
                float jx2 = s_bx[gj * 4 + 2], jy2 = s_bx[gj * 4 + 3];
                float aj = (jy2 - jy1) * (jx2 - jx1);
                int dead = 0;
                for (int i = 0; i < t0 && !dead; ++i) {
                    if (!s_keep[i]) continue;
                    float ix1 = s_bx[i * 4 + 0], iy1 = s_bx[i * 4 + 1];
                    float ix2 = s_bx[i * 4 + 2], iy2 = s_bx[i * 4 + 3];
                    float ai = (iy2 - iy1) * (ix2 - ix1);
                    float ih = fminf(iy2, jy2) - fmaxf(iy1, jy1);
                    ih = fmaxf(ih, 0.0f);
                    float iw = fminf(ix2, jx2) - fmaxf(ix1, jx1);
                    iw = fmaxf(iw, 0.0f);
                    float inter = ih * iw;
                    float uni = ai + aj - inter;
                    float iou = (inter > 0.0f) ? inter / fmaxf(uni, 1e-08f) : 0.0f;
                    dead = iou > NMS_IOU_TH;
                }
                if (dead) s_keep[gj] = 0;
            }
            __syncthreads();
        }

        // A: column suppressor masks. Outer loop over word wi, inner over j:
        // lanes share wi and sweep consecutive j -> the i-loop reads of
        // s_bx[gi..] are wave-broadcast (conflict-free); per-task j-box reads
        // are 4 stride-4 loads (8-way conflict, amortized over <=32 IoUs).
        for (int wi = 0; wi < NMS_TW; ++wi) {
            const int ibase = wi << 5;
            for (int j = threadIdx.x; j < tm; j += blockDim.x) {
                unsigned int msk = 0;
                int iend = j - ibase;            // only i < j
                if (iend > 32) iend = 32;
                if (iend > 0) {
                    const int gj = t0 + j;
                    float jx1 = s_bx[gj * 4 + 0], jy1 = s_bx[gj * 4 + 1];
                    float jx2 = s_bx[gj * 4 + 2], jy2 = s_bx[gj * 4 + 3];
                    float aj = (jy2 - jy1) * (jx2 - jx1);
                    for (int bb = 0; bb < iend; ++bb) {
                        const int gi = t0 + ibase + bb;   // broadcast read
                        float ix1 = s_bx[gi * 4 + 0], iy1 = s_bx[gi * 4 + 1];
                        float ix2 = s_bx[gi * 4 + 2], iy2 = s_bx[gi * 4 + 3];
                        float ai = (iy2 - iy1) * (ix2 - ix1);
                        float ih = fminf(iy2, jy2) - fmaxf(iy1, jy1);
                        ih = fmaxf(ih, 0.0f);
                        float iw = fminf(ix2, jx2) - fmaxf(ix1, jx1);
                        iw = fmaxf(iw, 0.0f);
                        float inter = ih * iw;
                        float uni = ai + aj - inter;
                        float iou = (inter > 0.0f) ? inter / fmaxf(uni, 1e-08f) : 0.0f;
                        if (iou > NMS_IOU_TH) msk |= (1u << bb);
                    }
                }
                s_supc[j * NMS_TW + wi] = msk;
            }
        }

        // Jacobi init: thread j owns tile candidate j (j < NMS_TILE).
        const int j = threadIdx.x;
        int ext = 0;                 // pre-suppression state (A0 deaths final)
        if (j < tm) ext = s_keep[t0 + j];
        int alive = ext;
        __syncthreads();             // supc complete; also orders s_keep reads

        // publish initial keep words via ballot (j < 128 -> waves 0,1)
        {
            unsigned long long bal = __ballot(alive != 0);
            if ((threadIdx.x & 63) == 0 && threadIdx.x < NMS_TILE) {
                s_kwds[(threadIdx.x >> 6) * 2 + 0] = (unsigned int)(bal & 0xffffffffu);
                s_kwds[(threadIdx.x >> 6) * 2 + 1] = (unsigned int)(bal >> 32);
            }
            if (threadIdx.x == 0) s_changed = 0;
        }
        __syncthreads();

        // Jacobi rounds: alive[j] = ext[j] && !(any suppressor i<j alive).
        // Converges to the unique greedy fixpoint in <= tm rounds (induction
        // on j); random data stabilizes in ~2-3 rounds.
        for (int round = 0; round < tm; ++round) {
            int newalive = 0;
            if (j < tm && ext) {
                unsigned int any = (s_supc[j * NMS_TW + 0] & s_kwds[0])
                                 | (s_supc[j * NMS_TW + 1] & s_kwds[1])
                                 | (s_supc[j * NMS_TW + 2] & s_kwds[2])
                                 | (s_supc[j * NMS_TW + 3] & s_kwds[3]);
                newalive = (any == 0);
            }
            int ch = (newalive != alive);
            alive = newalive;
            __syncthreads();                       // kwds reads done
            {
                unsigned long long bal = __ballot(alive != 0);
                if ((threadIdx.x & 63) == 0 && threadIdx.x < NMS_TILE) {
                    s_kwds[(threadIdx.x >> 6) * 2 + 0] = (unsigned int)(bal & 0xffffffffu);
                    s_kwds[(threadIdx.x >> 6) * 2 + 1] = (unsigned int)(bal >> 32);
                }
                if (ch) s_changed = 1;             // benign same-value race
            }
            __syncthreads();                       // kwds + flag visible
            int done = (s_changed == 0);
            __syncthreads();                       // all read flag
            if (threadIdx.x == 0) s_changed = 0;
            if (done) break;
        }

        // write back final tile state
        if (j < tm) s_keep[t0 + j] = (unsigned char)alive;
        __syncthreads();
    }

    // --- emit top-100 kept in sorted order via wave-scan (r12-proven) ---
    const int chunk = (M + 255) / 256;           // contiguous slots per thread
    const int lo = threadIdx.x * chunk;
    const int hi = (lo + chunk < M) ? (lo + chunk) : M;
    int cnt = 0;
    for (int jj = lo; jj < hi; ++jj) cnt += s_keep[jj];
    s_part[threadIdx.x] = cnt;
    __syncthreads();
    if (threadIdx.x < 64) {
        const int base = threadIdx.x * 4;
        int v0 = s_part[base + 0], v1 = s_part[base + 1];
        int v2 = s_part[base + 2], v3 = s_part[base + 3];
        int sum = v0 + v1 + v2 + v3;
        int inc = sum;
        for (int off = 1; off < 64; off <<= 1) {
            int n = __shfl_up(inc, off, 64);
            if ((int)threadIdx.x >= off) inc += n;
        }
        int exc = inc - sum;
        s_part[base + 0] = exc;
        s_part[base + 1] = exc + v0;
        s_part[base + 2] = exc + v0 + v1;
        s_part[base + 3] = exc + v0 + v1 + v2;
        if (threadIdx.x == 63) s_total = inc;
    }
    __syncthreads();

    float* osc = ws_scores + ((size_t)b * NMS_NUM_CLASSES + c) * NMS_MAX_PER_CLASS;
    float* obx = ws_boxes + (((size_t)b * NMS_NUM_CLASSES + c) * NMS_MAX_PER_CLASS) * 4;
    int pos = s_part[threadIdx.x];
    for (int jj = lo; jj < hi; ++jj) {
        if (s_keep[jj]) {
            if (pos < NMS_MAX_PER_CLASS) {
                osc[pos] = s_sc[jj];
                obx[pos * 4 + 0] = s_bx[jj * 4 + 0];
                obx[pos * 4 + 1] = s_bx[jj * 4 + 1];
                obx[pos * 4 + 2] = s_bx[jj * 4 + 2];
                obx[pos * 4 + 3] = s_bx[jj * 4 + 3];
            }
            pos++;
        }
    }
    // pad positions [total, 100) with -1
    if (threadIdx.x < NMS_MAX_PER_CLASS && threadIdx.x >= s_total)
        osc[threadIdx.x] = -1.0f;
}

// ---------------------------------------------------------------------------
// Kernel 2: one block per (image, class), 256 threads. Task-parallel partial
// ranks. BYTE-IDENTICAL to round-12 (passed, absmax 0).
// ---------------------------------------------------------------------------
__global__ __launch_bounds__(256) void nms_topk_kernel(
    const float* __restrict__ ws_scores,   // [B, 1600]
    const float* __restrict__ ws_boxes,    // [B, 1600, 4]
    float* __restrict__ out,               // [B*600] rows + [B] nvalid
    int B)
{
    const int b = blockIdx.x / NMS_NUM_CLASSES;
    const int c = blockIdx.x % NMS_NUM_CLASSES;
    const int cbase = c * NMS_MAX_PER_CLASS;
    __shared__ float s_sc[NMS_NS];
    __shared__ int s_rank[NMS_MAX_PER_CLASS];

    const float* isc = ws_scores + (size_t)b * NMS_NS;
    for (int t = threadIdx.x; t < NMS_NS; t += blockDim.x) s_sc[t] = isc[t];
    if (threadIdx.x < NMS_MAX_PER_CLASS) s_rank[threadIdx.x] = 0;
    __syncthreads();

    for (int task = threadIdx.x; task < NMS_MAX_PER_CLASS * 16; task += blockDim.x) {
        const int slot = task % NMS_MAX_PER_CLASS;
        const int chunk = task / NMS_MAX_PER_CLASS;
        const int flat = cbase + slot;
        const float s = s_sc[flat];
        const int j0 = chunk * 100;
        int rk = 0;
        for (int j = j0; j < j0 + 100; ++j) {
            float sj = s_sc[j];
            rk += (sj > s) || (sj == s && j < flat);
        }
        if (rk) atomicAdd(&s_rank[slot], rk);
    }
    __syncthreads();

    int is_top = 0;
    const int t = threadIdx.x;
    if (t < NMS_MAX_PER_CLASS) {
        const int slot = cbase + t;
        float s = s_sc[slot];
        if (s > NMS_SCORE_TH) {
            int rk = s_rank[t];
            if (rk < NMS_MAX_DET) {
                const float* bx = ws_boxes + ((size_t)b * NMS_NS + slot) * 4;
                float* row = out + (size_t)b * NMS_MAX_DET * 6 + rk * 6;
                row[0] = bx[0];
                row[1] = bx[1];
                row[2] = bx[2];
                row[3] = bx[3];
                row[4] = (float)c;
                row[5] = s;
                is_top = 1;
            }
        }
    }
    unsigned long long m = __ballot(is_top);
    if ((threadIdx.x & 63) == 0) {
        float cnt = (float)__popcll(m);
        if (cnt > 0.0f)
            atomicAdd(&out[(size_t)B * NMS_MAX_DET * 6 + b], cnt);
    }
}

extern "C" void kernel_launch(void* const* d_in, const int* in_sizes, int n_in,
                              void* d_out, int out_size, void* d_ws, size_t ws_size,
                              hipStream_t stream) {
    const float* pred = (const float*)d_in[0];
    const int B = in_sizes[0] / (NMS_N * 6);
    if (B <= 0) return;
    float* out = (float*)d_out;

    float* ws_scores = (float*)d_ws;
    float* ws_boxes = ws_scores + (size_t)B * NMS_NS;

    nms_per_class_kernel<<<dim3(B * NMS_NUM_CLASSES), dim3(256), 0, stream>>>(
        pred, ws_scores, ws_boxes, out, B);
    nms_topk_kernel<<<dim3(B * NMS_NUM_CLASSES), dim3(256), 0, stream>>>(
        ws_scores, ws_boxes, out, B);
}

// Round 16
// 112.479 us; speedup vs baseline: 1.4052x; 1.1621x over previous
//
#include <hip/hip_runtime.h>

#define NMS_NUM_CLASSES 16
#define NMS_N 2048
#define NMS_IOU_TH 0.5f
#define NMS_SCORE_TH 0.05f
#define NMS_MAX_DET 100
#define NMS_MAX_PER_CLASS 100
#define NMS_NS (NMS_NUM_CLASSES * NMS_MAX_PER_CLASS)   // 1600
#define NMS_TILE 128
#define NMS_TW 4                     // u32 words per column mask (128 bits)

// SESSION PITFALLS (r1-r15):
//  * float4 casts on __shared__ float -> ds_read_b128 misalignment fault.
//  * u64 LDS arrays / LDS pointer casts correlated with container deaths.
//    ONLY declared __shared__ float/uint/uchar arrays, scalar access.
//  * Serial NMS chains cost 45-65 us at M~122 -> Jacobi fixpoint (r15, ~8us).
//  * k1 phases are latency-bound at 4 waves/CU (93% stall) -> 1024 threads
//    + task-parallel rank sort this round.

// ---------------------------------------------------------------------------
// Kernel 1: one block per (image, class), 1024 threads. Compact ->
// task-parallel rank sort -> column-mask + Jacobi NMS (r15-proven) ->
// wave-scan emit (first 256 threads). c==0 blocks zero image output.
// ---------------------------------------------------------------------------
__global__ __launch_bounds__(1024) void nms_per_class_kernel(
    const float* __restrict__ pred,   // [B, N, 6] x1,y1,x2,y2,cls,score
    float* __restrict__ ws_scores,    // [B, 1600]
    float* __restrict__ ws_boxes,     // [B, 1600, 4]
    float* __restrict__ out,          // [B*600] rows + [B] nvalid
    int B)
{
    const int b = blockIdx.x / NMS_NUM_CLASSES;
    const int c = blockIdx.x % NMS_NUM_CLASSES;
    const float* p = pred + (size_t)b * NMS_N * 6;

    // zero-init output for this image (k2 is a later dispatch on the stream)
    if (c == 0) {
        float* ob = out + (size_t)b * NMS_MAX_DET * 6;
        for (int t = threadIdx.x; t < NMS_MAX_DET * 6; t += blockDim.x) ob[t] = 0.0f;
        if (threadIdx.x == 0) out[(size_t)B * NMS_MAX_DET * 6 + b] = 0.0f;
    }

    // unsorted candidate arrays
    __shared__ float s_scu[NMS_N];
    __shared__ int   s_ixu[NMS_N];
    __shared__ float s_bxu[NMS_N * 4];
    __shared__ int   s_rk[NMS_N];
    // sorted candidate arrays
    __shared__ float s_sc[NMS_N];
    __shared__ float s_bx[NMS_N * 4];
    __shared__ unsigned char s_keep[NMS_N];
    __shared__ unsigned int s_supc[NMS_TILE * NMS_TW];  // column masks, 2 KB
    __shared__ unsigned int s_kwds[NMS_TW];             // published keep bits
    __shared__ int s_m;
    __shared__ int s_part[256];
    __shared__ int s_total;
    __shared__ int s_changed;

    if (threadIdx.x == 0) s_m = 0;
    __syncthreads();

    // --- compact candidates of class c with score > TH (r12-proven) ---
    const float2* p2 = (const float2*)p;   // row i = p2[3i], p2[3i+1], p2[3i+2]
    for (int i = threadIdx.x; i < NMS_N; i += blockDim.x) {
        float2 v0 = p2[i * 3 + 0];   // x1, y1
        float2 v1 = p2[i * 3 + 1];   // x2, y2
        float2 v2 = p2[i * 3 + 2];   // cls, score
        if ((int)v2.x == c && v2.y > NMS_SCORE_TH) {
            int pos = atomicAdd(&s_m, 1);
            s_scu[pos] = v2.y;
            s_ixu[pos] = i;
            s_bxu[pos * 4 + 0] = v0.x;
            s_bxu[pos * 4 + 1] = v0.y;
            s_bxu[pos * 4 + 2] = v1.x;
            s_bxu[pos * 4 + 3] = v1.y;
        }
    }
    __syncthreads();
    const int M = s_m;

    // --- task-parallel rank sort: rank[q] = #{j: (sj,ixj) orders before} ---
    // Same comparator as r12-proven serial version; decomposed into
    // (q, 32-chunk) tasks so the per-thread chain is 32 LDS reads, not M.
    for (int q = threadIdx.x; q < M; q += blockDim.x) s_rk[q] = 0;
    __syncthreads();
    {
        const int nch = (M + 31) >> 5;
        const int ntask = M * nch;
        for (int task = threadIdx.x; task < ntask; task += blockDim.x) {
            const int q = task % M;          // consecutive tids -> distinct q
            const int ch = task / M;
            const float sq = s_scu[q];
            const int   iq = s_ixu[q];
            const int j0 = ch << 5;
            int jend = j0 + 32; if (jend > M) jend = M;
            int rk = 0;
            for (int j = j0; j < jend; ++j) {
                float sj = s_scu[j];
                rk += (sj > sq) || (sj == sq && s_ixu[j] < iq);
            }
            if (rk) atomicAdd(&s_rk[q], rk);
        }
    }
    __syncthreads();
    for (int q = threadIdx.x; q < M; q += blockDim.x) {
        int rk = s_rk[q];
        s_sc[rk] = s_scu[q];
        s_bx[rk * 4 + 0] = s_bxu[q * 4 + 0];
        s_bx[rk * 4 + 1] = s_bxu[q * 4 + 1];
        s_bx[rk * 4 + 2] = s_bxu[q * 4 + 2];
        s_bx[rk * 4 + 3] = s_bxu[q * 4 + 3];
        s_keep[rk] = 1;
    }
    __syncthreads();

    // --- tiled NMS: column masks + Jacobi fixpoint per tile (r15-proven) ---
    for (int t0 = 0; t0 < M; t0 += NMS_TILE) {
        const int tm = (M - t0 < NMS_TILE) ? (M - t0) : NMS_TILE;

        // A0: suppression by kept candidates of earlier tiles (final state)
        if (t0 > 0) {
            for (int j = threadIdx.x; j < tm; j += blockDim.x) {
                const int gj = t0 + j;
                float jx1 = s_bx[gj * 4 + 0], jy1 = s_bx[gj * 4 + 1];
                float jx2 = s_bx[gj * 4 + 2], jy2 = s_bx[gj * 4 + 3];
                float aj = (jy2 - jy1) * (jx2 - jx1);
                int dead = 0;
                for (int i = 0; i < t0 && !dead; ++i) {
                    if (!s_keep[i]) continue;
                    float ix1 = s_bx[i * 4 + 0], iy1 = s_bx[i * 4 + 1];
                    float ix2 = s_bx[i * 4 + 2], iy2 = s_bx[i * 4 + 3];
                    float ai = (iy2 - iy1) * (ix2 - ix1);
                    float ih = fminf(iy2, jy2) - fmaxf(iy1, jy1);
                    ih = fmaxf(ih, 0.0f);
                    float iw = fminf(ix2, jx2) - fmaxf(ix1, jx1);
                    iw = fmaxf(iw, 0.0f);
                    float inter = ih * iw;
                    float uni = ai + aj - inter;
                    float iou = (inter > 0.0f) ? inter / fmaxf(uni, 1e-08f) : 0.0f;
                    dead = iou > NMS_IOU_TH;
                }
                if (dead) s_keep[gj] = 0;
            }
            __syncthreads();
        }

        // A: column suppressor masks — (wi, j) task space in one sweep.
        // Lanes sweep consecutive j at fixed wi -> i-box reads broadcast.
        for (int idx = threadIdx.x; idx < NMS_TW * tm; idx += blockDim.x) {
            const int wi = idx / tm;
            const int j = idx % tm;
            const int ibase = wi << 5;
            unsigned int msk = 0;
            int iend = j - ibase;            // only i < j
            if (iend > 32) iend = 32;
            if (iend > 0) {
                const int gj = t0 + j;
                float jx1 = s_bx[gj * 4 + 0], jy1 = s_bx[gj * 4 + 1];
                float jx2 = s_bx[gj * 4 + 2], jy2 = s_bx[gj * 4 + 3];
                float aj = (jy2 - jy1) * (jx2 - jx1);
                for (int bb = 0; bb < iend; ++bb) {
                    const int gi = t0 + ibase + bb;
                    float ix1 = s_bx[gi * 4 + 0], iy1 = s_bx[gi * 4 + 1];
                    float ix2 = s_bx[gi * 4 + 2], iy2 = s_bx[gi * 4 + 3];
                    float ai = (iy2 - iy1) * (ix2 - ix1);
                    float ih = fminf(iy2, jy2) - fmaxf(iy1, jy1);
                    ih = fmaxf(ih, 0.0f);
                    float iw = fminf(ix2, jx2) - fmaxf(ix1, jx1);
                    iw = fmaxf(iw, 0.0f);
                    float inter = ih * iw;
                    float uni = ai + aj - inter;
                    float iou = (inter > 0.0f) ? inter / fmaxf(uni, 1e-08f) : 0.0f;
                    if (iou > NMS_IOU_TH) msk |= (1u << bb);
                }
            }
            s_supc[j * NMS_TW + wi] = msk;
        }

        // Jacobi init: thread j owns tile candidate j
        const int j = threadIdx.x;
        int ext = 0;                 // pre-suppression state (A0 deaths final)
        if (j < tm) ext = s_keep[t0 + j];
        int alive = ext;
        __syncthreads();             // supc complete

        {
            unsigned long long bal = __ballot(alive != 0);
            if ((threadIdx.x & 63) == 0 && threadIdx.x < NMS_TILE) {
                s_kwds[(threadIdx.x >> 6) * 2 + 0] = (unsigned int)(bal & 0xffffffffu);
                s_kwds[(threadIdx.x >> 6) * 2 + 1] = (unsigned int)(bal >> 32);
            }
            if (threadIdx.x == 0) s_changed = 0;
        }
        __syncthreads();

        for (int round = 0; round < tm; ++round) {
            int newalive = 0;
            if (j < tm && ext) {
                unsigned int any = (s_supc[j * NMS_TW + 0] & s_kwds[0])
                                 | (s_supc[j * NMS_TW + 1] & s_kwds[1])
                                 | (s_supc[j * NMS_TW + 2] & s_kwds[2])
                                 | (s_supc[j * NMS_TW + 3] & s_kwds[3]);
                newalive = (any == 0);
            }
            int ch = (newalive != alive);
            alive = newalive;
            __syncthreads();                       // kwds reads done
            {
                unsigned long long bal = __ballot(alive != 0);
                if ((threadIdx.x & 63) == 0 && threadIdx.x < NMS_TILE) {
                    s_kwds[(threadIdx.x >> 6) * 2 + 0] = (unsigned int)(bal & 0xffffffffu);
                    s_kwds[(threadIdx.x >> 6) * 2 + 1] = (unsigned int)(bal >> 32);
                }
                if (ch) s_changed = 1;             // benign same-value race
            }
            __syncthreads();                       // kwds + flag visible
            int done = (s_changed == 0);
            __syncthreads();                       // all read flag
            if (threadIdx.x == 0) s_changed = 0;
            if (done) break;
        }

        if (j < tm) s_keep[t0 + j] = (unsigned char)alive;
        __syncthreads();
    }

    // --- emit top-100 kept in sorted order (first 256 threads; r12-proven) ---
    const int chunk = (M + 255) / 256;           // contiguous slots per thread
    int lo = 0, hi = 0;
    if (threadIdx.x < 256) {
        lo = threadIdx.x * chunk;
        hi = (lo + chunk < M) ? (lo + chunk) : M;
        int cnt = 0;
        for (int jj = lo; jj < hi; ++jj) cnt += s_keep[jj];
        s_part[threadIdx.x] = cnt;
    }
    __syncthreads();
    if (threadIdx.x < 64) {
        const int base = threadIdx.x * 4;
        int v0 = s_part[base + 0], v1 = s_part[base + 1];
        int v2 = s_part[base + 2], v3 = s_part[base + 3];
        int sum = v0 + v1 + v2 + v3;
        int inc = sum;
        for (int off = 1; off < 64; off <<= 1) {
            int n = __shfl_up(inc, off, 64);
            if ((int)threadIdx.x >= off) inc += n;
        }
        int exc = inc - sum;
        s_part[base + 0] = exc;
        s_part[base + 1] = exc + v0;
        s_part[base + 2] = exc + v0 + v1;
        s_part[base + 3] = exc + v0 + v1 + v2;
        if (threadIdx.x == 63) s_total = inc;
    }
    __syncthreads();

    float* osc = ws_scores + ((size_t)b * NMS_NUM_CLASSES + c) * NMS_MAX_PER_CLASS;
    float* obx = ws_boxes + (((size_t)b * NMS_NUM_CLASSES + c) * NMS_MAX_PER_CLASS) * 4;
    if (threadIdx.x < 256) {
        int pos = s_part[threadIdx.x];
        for (int jj = lo; jj < hi; ++jj) {
            if (s_keep[jj]) {
                if (pos < NMS_MAX_PER_CLASS) {
                    osc[pos] = s_sc[jj];
                    obx[pos * 4 + 0] = s_bx[jj * 4 + 0];
                    obx[pos * 4 + 1] = s_bx[jj * 4 + 1];
                    obx[pos * 4 + 2] = s_bx[jj * 4 + 2];
                    obx[pos * 4 + 3] = s_bx[jj * 4 + 3];
                }
                pos++;
            }
        }
    }
    // pad positions [total, 100) with -1
    if (threadIdx.x < NMS_MAX_PER_CLASS && threadIdx.x >= s_total)
        osc[threadIdx.x] = -1.0f;
}

// ---------------------------------------------------------------------------
// Kernel 2: one block per (image, class), 256 threads. Task-parallel partial
// ranks. BYTE-IDENTICAL to round-12 (passed, absmax 0).
// ---------------------------------------------------------------------------
__global__ __launch_bounds__(256) void nms_topk_kernel(
    const float* __restrict__ ws_scores,   // [B, 1600]
    const float* __restrict__ ws_boxes,    // [B, 1600, 4]
    float* __restrict__ out,               // [B*600] rows + [B] nvalid
    int B)
{
    const int b = blockIdx.x / NMS_NUM_CLASSES;
    const int c = blockIdx.x % NMS_NUM_CLASSES;
    const int cbase = c * NMS_MAX_PER_CLASS;
    __shared__ float s_sc[NMS_NS];
    __shared__ int s_rank[NMS_MAX_PER_CLASS];

    const float* isc = ws_scores + (size_t)b * NMS_NS;
    for (int t = threadIdx.x; t < NMS_NS; t += blockDim.x) s_sc[t] = isc[t];
    if (threadIdx.x < NMS_MAX_PER_CLASS) s_rank[threadIdx.x] = 0;
    __syncthreads();

    for (int task = threadIdx.x; task < NMS_MAX_PER_CLASS * 16; task += blockDim.x) {
        const int slot = task % NMS_MAX_PER_CLASS;
        const int chunk = task / NMS_MAX_PER_CLASS;
        const int flat = cbase + slot;
        const float s = s_sc[flat];
        const int j0 = chunk * 100;
        int rk = 0;
        for (int j = j0; j < j0 + 100; ++j) {
            float sj = s_sc[j];
            rk += (sj > s) || (sj == s && j < flat);
        }
        if (rk) atomicAdd(&s_rank[slot], rk);
    }
    __syncthreads();

    int is_top = 0;
    const int t = threadIdx.x;
    if (t < NMS_MAX_PER_CLASS) {
        const int slot = cbase + t;
        float s = s_sc[slot];
        if (s > NMS_SCORE_TH) {
            int rk = s_rank[t];
            if (rk < NMS_MAX_DET) {
                const float* bx = ws_boxes + ((size_t)b * NMS_NS + slot) * 4;
                float* row = out + (size_t)b * NMS_MAX_DET * 6 + rk * 6;
                row[0] = bx[0];
                row[1] = bx[1];
                row[2] = bx[2];
                row[3] = bx[3];
                row[4] = (float)c;
                row[5] = s;
                is_top = 1;
            }
        }
    }
    unsigned long long m = __ballot(is_top);
    if ((threadIdx.x & 63) == 0) {
        float cnt = (float)__popcll(m);
        if (cnt > 0.0f)
            atomicAdd(&out[(size_t)B * NMS_MAX_DET * 6 + b], cnt);
    }
}

extern "C" void kernel_launch(void* const* d_in, const int* in_sizes, int n_in,
                              void* d_out, int out_size, void* d_ws, size_t ws_size,
                              hipStream_t stream) {
    const float* pred = (const float*)d_in[0];
    const int B = in_sizes[0] / (NMS_N * 6);
    if (B <= 0) return;
    float* out = (float*)d_out;

    float* ws_scores = (float*)d_ws;
    float* ws_boxes = ws_scores + (size_t)B * NMS_NS;

    nms_per_class_kernel<<<dim3(B * NMS_NUM_CLASSES), dim3(1024), 0, stream>>>(
        pred, ws_scores, ws_boxes, out, B);
    nms_topk_kernel<<<dim3(B * NMS_NUM_CLASSES), dim3(256), 0, stream>>>(
        ws_scores, ws_boxes, out, B);
}